// Round 1
// baseline (83.210 us; speedup 1.0000x reference)
//
#include <hip/hip_runtime.h>
#include <hip/hip_bf16.h>

#define IN_FEATS 64
#define OUT_FEATS 64
#define K_NEIGH 7
#define KDIM (K_NEIGH * IN_FEATS)   // 448
#define KSTEPS (KDIM / 32)          // 14

typedef __bf16 bf16x8 __attribute__((ext_vector_type(8)));
typedef float  f32x4  __attribute__((ext_vector_type(4)));

__device__ __forceinline__ unsigned short f2bf(float f) {
    union { float f; unsigned int u; } v; v.f = f;
    unsigned int u = v.u;
    // round-to-nearest-even
    unsigned int r = (u + 0x7FFFu + ((u >> 16) & 1u)) >> 16;
    return (unsigned short)r;
}

// out[n][64] = sum_k sum_c x[neigh[n*7+k]][c] * W[o][k*64+c] + b[o]
__global__ __launch_bounds__(256, 2)
void onering_mfma(const float* __restrict__ x,
                  const int*   __restrict__ neigh,
                  const float* __restrict__ W,
                  const float* __restrict__ b,
                  float* __restrict__ out,
                  int n)
{
    // W staged as bf16 [64][448], XOR-swizzled: byte ^= ((row&7)<<4)
    __shared__ unsigned short wlds[OUT_FEATS * KDIM];   // 57344 B

    const int tid  = threadIdx.x;
    const int wid  = tid >> 6;
    const int lane = tid & 63;

    // ---- stage W (fp32 -> bf16) into swizzled LDS ----
    // 28672 floats = 7168 float4; 256 threads -> 28 each
    for (int i = tid; i < (OUT_FEATS * KDIM) / 4; i += 256) {
        f32x4 w4 = *(const f32x4*)(W + i * 4);
        int e   = i * 4;
        int row = e / KDIM;               // all 4 elems same row (448 % 4 == 0)
        ushort4 h;
        h.x = f2bf(w4.x); h.y = f2bf(w4.y); h.z = f2bf(w4.z); h.w = f2bf(w4.w);
        int byteoff = e * 2;              // row*896 + col*2 (col*2 % 8 == 0)
        byteoff ^= ((row & 7) << 4);      // granule swizzle, 8B chunk stays inside 16B granule
        *(ushort4*)((char*)wlds + byteoff) = h;
    }
    __syncthreads();

    const int rowbase = (blockIdx.x * 4 + wid) * 64;   // this wave's 64 rows
    const int lhi = lane >> 4;            // 0..3
    const int llo = lane & 15;            // 0..15

    // preload the 7 neighbor indices for each of this lane's 4 row-tiles
    int nidx[4][K_NEIGH];
    #pragma unroll
    for (int rt = 0; rt < 4; ++rt) {
        int r  = rowbase + rt * 16 + llo;
        int rr = (r < n) ? r : 0;         // clamp OOB rows (stores are guarded)
        #pragma unroll
        for (int kn = 0; kn < K_NEIGH; ++kn)
            nidx[rt][kn] = neigh[rr * K_NEIGH + kn];
    }

    f32x4 acc[4][4] = {};   // [rowtile][coltile], zero-init

    for (int kk = 0; kk < KSTEPS; ++kk) {
        const int kn   = kk >> 1;
        const int foff = (kk & 1) * 32;

        // B fragments: lane reads W[ocol][klocal .. klocal+7] from swizzled LDS
        bf16x8 bfrag[4];
        const int klocal = kk * 32 + lhi * 8;
        #pragma unroll
        for (int ct = 0; ct < 4; ++ct) {
            int ocol    = ct * 16 + llo;
            int byteoff = ocol * (KDIM * 2) + klocal * 2;
            byteoff ^= ((ocol & 7) << 4);
            bfrag[ct] = *(const bf16x8*)((const char*)wlds + byteoff);
        }

        #pragma unroll
        for (int rt = 0; rt < 4; ++rt) {
            const int src = nidx[rt][kn];
            const float* xp = x + (long)src * IN_FEATS + foff + lhi * 8;
            f32x4 a0 = *(const f32x4*)xp;
            f32x4 a1 = *(const f32x4*)(xp + 4);
            bf16x8 af;
            af[0] = (__bf16)a0.x; af[1] = (__bf16)a0.y;
            af[2] = (__bf16)a0.z; af[3] = (__bf16)a0.w;
            af[4] = (__bf16)a1.x; af[5] = (__bf16)a1.y;
            af[6] = (__bf16)a1.z; af[7] = (__bf16)a1.w;
            #pragma unroll
            for (int ct = 0; ct < 4; ++ct)
                acc[rt][ct] = __builtin_amdgcn_mfma_f32_16x16x32_bf16(
                                  af, bfrag[ct], acc[rt][ct], 0, 0, 0);
        }
    }

    // ---- epilogue: bias + store (C/D layout: col = lane&15, row = (lane>>4)*4 + reg) ----
    #pragma unroll
    for (int ct = 0; ct < 4; ++ct) {
        float bias = b[ct * 16 + llo];
        #pragma unroll
        for (int rt = 0; rt < 4; ++rt)
            #pragma unroll
            for (int j = 0; j < 4; ++j)
                acc[rt][ct][j] += bias;
    }

    #pragma unroll
    for (int rt = 0; rt < 4; ++rt) {
        const int rbase = rowbase + rt * 16 + lhi * 4;
        #pragma unroll
        for (int j = 0; j < 4; ++j) {
            const int r = rbase + j;
            if (r < n) {
                #pragma unroll
                for (int ct = 0; ct < 4; ++ct)
                    out[(long)r * OUT_FEATS + ct * 16 + llo] = acc[rt][ct][j];
            }
        }
    }
}

extern "C" void kernel_launch(void* const* d_in, const int* in_sizes, int n_in,
                              void* d_out, int out_size, void* d_ws, size_t ws_size,
                              hipStream_t stream) {
    const float* x     = (const float*)d_in[0];
    const int*   neigh = (const int*)d_in[1];
    const float* W     = (const float*)d_in[2];
    const float* b     = (const float*)d_in[3];
    float* out = (float*)d_out;

    const int n = in_sizes[0] / IN_FEATS;          // 163842
    const int nblocks = (n + 255) / 256;           // 641, 256 rows per block

    onering_mfma<<<dim3(nblocks), dim3(256), 0, stream>>>(x, neigh, W, b, out, n);
}

// Round 2
// 50.844 us; speedup vs baseline: 1.6366x; 1.6366x over previous
//
#include <hip/hip_runtime.h>
#include <hip/hip_bf16.h>

#define IN_FEATS 64
#define OUT_FEATS 64
#define K_NEIGH 7
#define KDIM (K_NEIGH * IN_FEATS)   // 448
#define KSTEPS (KDIM / 32)          // 14

typedef __bf16 bf16x8 __attribute__((ext_vector_type(8)));
typedef float  f32x4  __attribute__((ext_vector_type(4)));

__device__ __forceinline__ unsigned short f2bf(float f) {
    union { float f; unsigned int u; } v; v.f = f;
    unsigned int u = v.u;
    unsigned int r = (u + 0x7FFFu + ((u >> 16) & 1u)) >> 16;   // RNE
    return (unsigned short)r;
}

// ---- kernel 1: cast x fp32 -> bf16 (row layout unchanged [N][64]) ----
__global__ __launch_bounds__(256)
void cast_x_bf16(const float* __restrict__ x, __bf16* __restrict__ xb, int total8) {
    int i = blockIdx.x * 256 + threadIdx.x;
    const int stride = gridDim.x * 256;
    for (; i < total8; i += stride) {
        f32x4 a0 = *(const f32x4*)(x + (long)i * 8);
        f32x4 a1 = *(const f32x4*)(x + (long)i * 8 + 4);
        bf16x8 o;
        o[0] = (__bf16)a0.x; o[1] = (__bf16)a0.y; o[2] = (__bf16)a0.z; o[3] = (__bf16)a0.w;
        o[4] = (__bf16)a1.x; o[5] = (__bf16)a1.y; o[6] = (__bf16)a1.z; o[7] = (__bf16)a1.w;
        *(bf16x8*)(xb + (long)i * 8) = o;
    }
}

// ---- kernel 2: gathered GEMM. 512 threads = 8 waves; wave owns 32 rows x 64 cols ----
template<bool PRECAST>
__global__ __launch_bounds__(512, 4)
void onering_mfma2(const float* __restrict__ x,
                   const __bf16* __restrict__ xb,
                   const int*   __restrict__ neigh,
                   const float* __restrict__ W,
                   const float* __restrict__ b,
                   float* __restrict__ out,
                   int n)
{
    // W staged as bf16 [64][448], XOR-swizzled: byte ^= ((row&7)<<4)
    __shared__ unsigned short wlds[OUT_FEATS * KDIM];   // 57344 B -> 2 blocks/CU

    const int tid  = threadIdx.x;
    const int wid  = tid >> 6;            // 0..7
    const int lane = tid & 63;
    const int lhi  = lane >> 4;           // 0..3
    const int llo  = lane & 15;           // 0..15

    // ---- stage W (fp32 -> bf16) into swizzled LDS ----
    for (int i = tid; i < (OUT_FEATS * KDIM) / 4; i += 512) {
        f32x4 w4 = *(const f32x4*)(W + i * 4);
        int e   = i * 4;
        int row = e / KDIM;
        ushort4 h;
        h.x = f2bf(w4.x); h.y = f2bf(w4.y); h.z = f2bf(w4.z); h.w = f2bf(w4.w);
        int byteoff = e * 2;
        byteoff ^= ((row & 7) << 4);
        *(ushort4*)((char*)wlds + byteoff) = h;
    }
    __syncthreads();

    const int rowbase = (blockIdx.x * 8 + wid) * 32;   // this wave's 32 rows

    // neighbor indices for the lane's 2 row-tiles
    int nidx[2][K_NEIGH];
    #pragma unroll
    for (int rt = 0; rt < 2; ++rt) {
        int r  = rowbase + rt * 16 + llo;
        int rr = (r < n) ? r : 0;
        #pragma unroll
        for (int kn = 0; kn < K_NEIGH; ++kn)
            nidx[rt][kn] = neigh[(long)rr * K_NEIGH + kn];
    }

    f32x4 acc[2][4] = {};

    #pragma unroll
    for (int kn = 0; kn < K_NEIGH; ++kn) {
        // gather A fragments for both K-halves of this neighbor (no barrier in loop:
        // compiler may hoist next-kn loads under current MFMAs)
        bf16x8 afr[2][2];
        #pragma unroll
        for (int rt = 0; rt < 2; ++rt) {
            const long src = nidx[rt][kn];
            if (PRECAST) {
                const __bf16* xp = xb + src * IN_FEATS + lhi * 8;
                afr[rt][0] = *(const bf16x8*)(xp);
                afr[rt][1] = *(const bf16x8*)(xp + 32);
            } else {
                const float* xp = x + src * IN_FEATS + lhi * 8;
                #pragma unroll
                for (int h = 0; h < 2; ++h) {
                    f32x4 a0 = *(const f32x4*)(xp + h * 32);
                    f32x4 a1 = *(const f32x4*)(xp + h * 32 + 4);
                    bf16x8 af;
                    af[0] = (__bf16)a0.x; af[1] = (__bf16)a0.y;
                    af[2] = (__bf16)a0.z; af[3] = (__bf16)a0.w;
                    af[4] = (__bf16)a1.x; af[5] = (__bf16)a1.y;
                    af[6] = (__bf16)a1.z; af[7] = (__bf16)a1.w;
                    afr[rt][h] = af;
                }
            }
        }

        #pragma unroll
        for (int h = 0; h < 2; ++h) {
            const int kk = kn * 2 + h;
            const int klocal = kk * 32 + lhi * 8;
            bf16x8 bfrag[4];
            #pragma unroll
            for (int ct = 0; ct < 4; ++ct) {
                int ocol    = ct * 16 + llo;
                int byteoff = ocol * (KDIM * 2) + klocal * 2;
                byteoff ^= ((ocol & 7) << 4);
                bfrag[ct] = *(const bf16x8*)((const char*)wlds + byteoff);
            }
            #pragma unroll
            for (int ct = 0; ct < 4; ++ct)
                #pragma unroll
                for (int rt = 0; rt < 2; ++rt)
                    acc[rt][ct] = __builtin_amdgcn_mfma_f32_16x16x32_bf16(
                                      afr[rt][h], bfrag[ct], acc[rt][ct], 0, 0, 0);
        }
    }

    // ---- epilogue: bias + guarded store (C/D: col = lane&15, row = (lane>>4)*4 + reg) ----
    #pragma unroll
    for (int ct = 0; ct < 4; ++ct) {
        float bias = b[ct * 16 + llo];
        #pragma unroll
        for (int rt = 0; rt < 2; ++rt)
            #pragma unroll
            for (int j = 0; j < 4; ++j)
                acc[rt][ct][j] += bias;
    }

    #pragma unroll
    for (int rt = 0; rt < 2; ++rt) {
        const int rbase = rowbase + rt * 16 + lhi * 4;
        #pragma unroll
        for (int j = 0; j < 4; ++j) {
            const int r = rbase + j;
            if (r < n) {
                #pragma unroll
                for (int ct = 0; ct < 4; ++ct)
                    out[(long)r * OUT_FEATS + ct * 16 + llo] = acc[rt][ct][j];
            }
        }
    }
}

extern "C" void kernel_launch(void* const* d_in, const int* in_sizes, int n_in,
                              void* d_out, int out_size, void* d_ws, size_t ws_size,
                              hipStream_t stream) {
    const float* x     = (const float*)d_in[0];
    const int*   neigh = (const int*)d_in[1];
    const float* W     = (const float*)d_in[2];
    const float* b     = (const float*)d_in[3];
    float* out = (float*)d_out;

    const int n = in_sizes[0] / IN_FEATS;              // 163842
    const int nblocks = (n + 255) / 256;               // 641 (256 rows per block)

    const size_t xb_bytes = (size_t)n * IN_FEATS * sizeof(unsigned short);
    if (ws_size >= xb_bytes) {
        __bf16* xb = (__bf16*)d_ws;
        const int total8 = n * IN_FEATS / 8;
        cast_x_bf16<<<dim3(2048), dim3(256), 0, stream>>>(x, xb, total8);
        onering_mfma2<true><<<dim3(nblocks), dim3(512), 0, stream>>>(
            x, xb, neigh, W, b, out, n);
    } else {
        onering_mfma2<false><<<dim3(nblocks), dim3(512), 0, stream>>>(
            x, nullptr, neigh, W, b, out, n);
    }
}

// Round 3
// 50.001 us; speedup vs baseline: 1.6642x; 1.0169x over previous
//
#include <hip/hip_runtime.h>
#include <hip/hip_bf16.h>

#define IN_FEATS 64
#define OUT_FEATS 64
#define K_NEIGH 7
#define KDIM (K_NEIGH * IN_FEATS)   // 448

typedef __bf16 bf16x8 __attribute__((ext_vector_type(8)));
typedef float  f32x4  __attribute__((ext_vector_type(4)));

__device__ __forceinline__ unsigned short f2bf(float f) {
    union { float f; unsigned int u; } v; v.f = f;
    unsigned int u = v.u;
    unsigned int r = (u + 0x7FFFu + ((u >> 16) & 1u)) >> 16;   // RNE
    return (unsigned short)r;
}

// ---- kernel 1: cast x fp32 -> bf16 (row layout unchanged [N][64]) ----
__global__ __launch_bounds__(256)
void cast_x_bf16(const float* __restrict__ x, __bf16* __restrict__ xb, int total8) {
    int i = blockIdx.x * 256 + threadIdx.x;
    const int stride = gridDim.x * 256;
    for (; i < total8; i += stride) {
        f32x4 a0 = *(const f32x4*)(x + (long)i * 8);
        f32x4 a1 = *(const f32x4*)(x + (long)i * 8 + 4);
        bf16x8 o;
        o[0] = (__bf16)a0.x; o[1] = (__bf16)a0.y; o[2] = (__bf16)a0.z; o[3] = (__bf16)a0.w;
        o[4] = (__bf16)a1.x; o[5] = (__bf16)a1.y; o[6] = (__bf16)a1.z; o[7] = (__bf16)a1.w;
        *(bf16x8*)(xb + (long)i * 8) = o;
    }
}

// ---- kernel 2: gathered GEMM, depth-2 gather pipeline ----
// 512 threads = 8 waves; wave owns 32 rows x 64 cols
template<bool PRECAST>
__global__ __launch_bounds__(512, 4)
void onering_mfma3(const float* __restrict__ x,
                   const __bf16* __restrict__ xb,
                   const int*   __restrict__ neigh,
                   const float* __restrict__ W,
                   const float* __restrict__ b,
                   float* __restrict__ out,
                   int n)
{
    // W staged as bf16 [64][448], XOR-swizzled: byte ^= ((row&7)<<4)
    __shared__ unsigned short wlds[OUT_FEATS * KDIM];   // 57344 B -> 2 blocks/CU

    const int tid  = threadIdx.x;
    const int wid  = tid >> 6;            // 0..7
    const int lane = tid & 63;
    const int lhi  = lane >> 4;           // 0..3
    const int llo  = lane & 15;           // 0..15

    // ---- stage W (fp32 -> bf16) into swizzled LDS (stores issued first) ----
    for (int i = tid; i < (OUT_FEATS * KDIM) / 4; i += 512) {
        f32x4 w4 = *(const f32x4*)(W + i * 4);
        int e   = i * 4;
        int row = e / KDIM;
        ushort4 h;
        h.x = f2bf(w4.x); h.y = f2bf(w4.y); h.z = f2bf(w4.z); h.w = f2bf(w4.w);
        int byteoff = e * 2;
        byteoff ^= ((row & 7) << 4);
        *(ushort4*)((char*)wlds + byteoff) = h;
    }

    const int rowbase = (blockIdx.x * 8 + wid) * 32;   // this wave's 32 rows

    // ---- neighbor indices (global loads, independent of LDS: overlap staging) ----
    int nidx[2][K_NEIGH];
    #pragma unroll
    for (int rt = 0; rt < 2; ++rt) {
        int r  = rowbase + rt * 16 + llo;
        int rr = (r < n) ? r : 0;
        #pragma unroll
        for (int kn = 0; kn < K_NEIGH; ++kn)
            nidx[rt][kn] = neigh[(long)rr * K_NEIGH + kn];
    }

    // gather of one neighbor's A-fragments (2 row-tiles x 2 K-halves)
    #define GATHER(dst, kn_)                                                   \
        do {                                                                   \
            _Pragma("unroll")                                                  \
            for (int rt = 0; rt < 2; ++rt) {                                   \
                const long src = nidx[rt][kn_];                                \
                if (PRECAST) {                                                 \
                    const __bf16* xp = xb + src * IN_FEATS + lhi * 8;          \
                    dst[rt][0] = *(const bf16x8*)(xp);                         \
                    dst[rt][1] = *(const bf16x8*)(xp + 32);                    \
                } else {                                                       \
                    const float* xp = x + src * IN_FEATS + lhi * 8;            \
                    _Pragma("unroll")                                          \
                    for (int h = 0; h < 2; ++h) {                              \
                        f32x4 a0 = *(const f32x4*)(xp + h * 32);               \
                        f32x4 a1 = *(const f32x4*)(xp + h * 32 + 4);           \
                        bf16x8 af;                                             \
                        af[0] = (__bf16)a0.x; af[1] = (__bf16)a0.y;            \
                        af[2] = (__bf16)a0.z; af[3] = (__bf16)a0.w;            \
                        af[4] = (__bf16)a1.x; af[5] = (__bf16)a1.y;            \
                        af[6] = (__bf16)a1.z; af[7] = (__bf16)a1.w;            \
                        dst[rt][h] = af;                                       \
                    }                                                          \
                }                                                              \
            }                                                                  \
        } while (0)

    // ---- prefetch kn=0 BEFORE the barrier: gather latency hides under staging ----
    bf16x8 afrA[2][2], afrB[2][2];
    GATHER(afrA, 0);

    f32x4 acc[2][4] = {};

    __syncthreads();

    #pragma unroll
    for (int kn = 0; kn < K_NEIGH; ++kn) {
        bf16x8 (&cur)[2][2] = (kn & 1) ? afrB : afrA;
        bf16x8 (&nxt)[2][2] = (kn & 1) ? afrA : afrB;

        // issue next neighbor's 4 gathers before this neighbor's MFMAs
        if (kn < K_NEIGH - 1)
            GATHER(nxt, kn + 1);

        #pragma unroll
        for (int h = 0; h < 2; ++h) {
            const int kk = kn * 2 + h;
            const int klocal = kk * 32 + lhi * 8;
            bf16x8 bfrag[4];
            #pragma unroll
            for (int ct = 0; ct < 4; ++ct) {
                int ocol    = ct * 16 + llo;
                int byteoff = ocol * (KDIM * 2) + klocal * 2;
                byteoff ^= ((ocol & 7) << 4);
                bfrag[ct] = *(const bf16x8*)((const char*)wlds + byteoff);
            }
            #pragma unroll
            for (int ct = 0; ct < 4; ++ct)
                #pragma unroll
                for (int rt = 0; rt < 2; ++rt)
                    acc[rt][ct] = __builtin_amdgcn_mfma_f32_16x16x32_bf16(
                                      cur[rt][h], bfrag[ct], acc[rt][ct], 0, 0, 0);
        }
    }
    #undef GATHER

    // ---- epilogue: bias + guarded store (C/D: col = lane&15, row = (lane>>4)*4 + reg) ----
    #pragma unroll
    for (int ct = 0; ct < 4; ++ct) {
        float bias = b[ct * 16 + llo];
        #pragma unroll
        for (int rt = 0; rt < 2; ++rt)
            #pragma unroll
            for (int j = 0; j < 4; ++j)
                acc[rt][ct][j] += bias;
    }

    #pragma unroll
    for (int rt = 0; rt < 2; ++rt) {
        const int rbase = rowbase + rt * 16 + lhi * 4;
        #pragma unroll
        for (int j = 0; j < 4; ++j) {
            const int r = rbase + j;
            if (r < n) {
                #pragma unroll
                for (int ct = 0; ct < 4; ++ct)
                    out[(long)r * OUT_FEATS + ct * 16 + llo] = acc[rt][ct][j];
            }
        }
    }
}

extern "C" void kernel_launch(void* const* d_in, const int* in_sizes, int n_in,
                              void* d_out, int out_size, void* d_ws, size_t ws_size,
                              hipStream_t stream) {
    const float* x     = (const float*)d_in[0];
    const int*   neigh = (const int*)d_in[1];
    const float* W     = (const float*)d_in[2];
    const float* b     = (const float*)d_in[3];
    float* out = (float*)d_out;

    const int n = in_sizes[0] / IN_FEATS;              // 163842
    const int nblocks = (n + 255) / 256;               // 641 (256 rows per block)

    const size_t xb_bytes = (size_t)n * IN_FEATS * sizeof(unsigned short);
    if (ws_size >= xb_bytes) {
        __bf16* xb = (__bf16*)d_ws;
        const int total8 = n * IN_FEATS / 8;
        cast_x_bf16<<<dim3(2048), dim3(256), 0, stream>>>(x, xb, total8);
        onering_mfma3<true><<<dim3(nblocks), dim3(512), 0, stream>>>(
            x, xb, neigh, W, b, out, n);
    } else {
        onering_mfma3<false><<<dim3(nblocks), dim3(512), 0, stream>>>(
            x, nullptr, neigh, W, b, out, n);
    }
}